// Round 3
// baseline (14.582 us; speedup 1.0000x reference)
//
#include <hip/hip_runtime.h>
#include <hip/hip_bf16.h>

// Closed-form of the 2-qubit circuit:
//   out0 = 0.5*(1 + cos(ry)*cos(x0) - sin(ry)*cos(rz)*sin(x0)*sin(x1))
//   out1 = 0.5*(1 + cos(ry)*cos(x1))
// (amplitudes are a*e^{-i rz/2} + b*e^{+i rz/2} with a,b real ->
//  |.|^2 = a^2+b^2+2ab*cos(rz); half-angle identities collapse the rest)

typedef float f32x4 __attribute__((ext_vector_type(4)));

// Exact-tiling path: grid*block*4 == n4, no predicates, no branches.
__global__ void __launch_bounds__(256)
qc2_expval_exact(const f32x4* __restrict__ x4,
                 const float* __restrict__ theta_rz,
                 const float* __restrict__ theta_ry,
                 f32x4* __restrict__ out4) {
    float ry = theta_ry[0];
    float cry = __cosf(ry);
    float srycrz = __sinf(ry) * __cosf(theta_rz[0]);

    int base   = blockIdx.x * blockDim.x + threadIdx.x;
    int stride = gridDim.x * blockDim.x;

    f32x4 v0 = x4[base];
    f32x4 v1 = x4[base + stride];
    f32x4 v2 = x4[base + 2 * stride];
    f32x4 v3 = x4[base + 3 * stride];

    f32x4 vv[4] = {v0, v1, v2, v3};
#pragma unroll
    for (int k = 0; k < 4; ++k) {
        float s0a, c0a, s1a, c1a, s0b, c0b, s1b, c1b;
        __sincosf(vv[k].x, &s0a, &c0a);
        __sincosf(vv[k].y, &s1a, &c1a);
        __sincosf(vv[k].z, &s0b, &c0b);
        __sincosf(vv[k].w, &s1b, &c1b);
        f32x4 o;
        o.x = 0.5f * (1.0f + cry * c0a - srycrz * s0a * s1a);
        o.y = 0.5f * (1.0f + cry * c1a);
        o.z = 0.5f * (1.0f + cry * c0b - srycrz * s0b * s1b);
        o.w = 0.5f * (1.0f + cry * c1b);
        __builtin_nontemporal_store(o, &out4[base + k * stride]);
    }
}

// Fallback: predicated grid-stride (any size).
__global__ void __launch_bounds__(256)
qc2_expval_generic(const f32x4* __restrict__ x4,
                   const float* __restrict__ theta_rz,
                   const float* __restrict__ theta_ry,
                   f32x4* __restrict__ out4,
                   int n4) {
    float ry = theta_ry[0];
    float cry = __cosf(ry);
    float srycrz = __sinf(ry) * __cosf(theta_rz[0]);

    int stride = gridDim.x * blockDim.x;
    for (int i = blockIdx.x * blockDim.x + threadIdx.x; i < n4; i += stride) {
        f32x4 v = x4[i];
        float s0a, c0a, s1a, c1a, s0b, c0b, s1b, c1b;
        __sincosf(v.x, &s0a, &c0a);
        __sincosf(v.y, &s1a, &c1a);
        __sincosf(v.z, &s0b, &c0b);
        __sincosf(v.w, &s1b, &c1b);
        f32x4 o;
        o.x = 0.5f * (1.0f + cry * c0a - srycrz * s0a * s1a);
        o.y = 0.5f * (1.0f + cry * c1a);
        o.z = 0.5f * (1.0f + cry * c0b - srycrz * s0b * s1b);
        o.w = 0.5f * (1.0f + cry * c1b);
        __builtin_nontemporal_store(o, &out4[i]);
    }
}

extern "C" void kernel_launch(void* const* d_in, const int* in_sizes, int n_in,
                              void* d_out, int out_size, void* d_ws, size_t ws_size,
                              hipStream_t stream) {
    const f32x4* x4       = (const f32x4*)d_in[0];   // [B,2] f32 -> B/2 float4
    const float* theta_rz = (const float*)d_in[1];
    const float* theta_ry = (const float*)d_in[2];
    f32x4* out4 = (f32x4*)d_out;

    int total_f = out_size;   // B*2 floats
    int n4 = total_f / 4;     // 2,097,152 for B = 4,194,304

    const int block = 256;
    const int grid = 2048;    // 8 blocks/CU
    if ((long long)grid * block * 4 == (long long)n4) {
        qc2_expval_exact<<<grid, block, 0, stream>>>(x4, theta_rz, theta_ry, out4);
    } else {
        int g = (n4 + block * 4 - 1) / (block * 4);
        if (g > grid) g = grid;
        if (g < 1) g = 1;
        qc2_expval_generic<<<g, block, 0, stream>>>(x4, theta_rz, theta_ry, out4, n4);
    }
}